// Round 1
// baseline (186.194 us; speedup 1.0000x reference)
//
#include <hip/hip_runtime.h>
#include <stdint.h>

#define NSEQ 2048

typedef __attribute__((ext_vector_type(4))) float f32x4;
typedef __attribute__((ext_vector_type(8))) short s16x8;
typedef _Float16 f16x8 __attribute__((ext_vector_type(8)));

// workspace byte offsets
#define OFF_XT  0u            // [3][4][2048][256] f16 = 12 MB (aliased later by XA)
#define OFF_W   12582912u     // 4 * 65536 f16 = 512 KB
#define OFF_QR  13107200u     // [16][2048][64] f16, 4 MB
#define OFF_KR  17301504u     // [16][2048][64]
#define OFF_VT  21495808u     // [16][64][2048]
#define OFF_XA  0u            // [4][2048][256] f16 (reuses XT region, dead by then)

__device__ __forceinline__ short f2h(float f) {
  _Float16 h = (_Float16)f;
  return __builtin_bit_cast(short, h);
}
// 64B-row tiles (GEMM staging, [128][32] f16): spread 4 slots with row bits
__device__ __forceinline__ int swz64(int row, int slot) {
  return row * 64 + ((slot ^ ((row >> 1) & 3)) << 4);
}
// 128B-row tiles (attention, [*][64] f16): classic ^(row&7) on the 16B slot
__device__ __forceinline__ int swz128(int row, int slot) {
  return row * 128 + ((slot ^ (row & 7)) << 4);
}
#define MFMA(a, b, c) __builtin_amdgcn_mfma_f32_16x16x32_f16(a, b, c, 0, 0, 0)

// ---------------- kernel 1: weight cast (+ Wm reorder to k = h*64+d) ----------------
__global__ void k_convw(const float* __restrict__ Wq, const float* __restrict__ Wk,
                        const float* __restrict__ Wv, const float* __restrict__ Wm,
                        char* __restrict__ ws) {
  int o = blockIdx.x, which = blockIdx.y, i = threadIdx.x;
  const float* src = which == 0 ? Wq : which == 1 ? Wk : which == 2 ? Wv : Wm;
  short* dst = (short*)(ws + OFF_W) + which * 65536;
  // Wm_r[o][h*64+d] = Wm[o][d*4+h]
  float val = (which < 3) ? src[o * 256 + i] : src[o * 256 + ((i & 63) << 2) + (i >> 6)];
  dst[o * 256 + i] = f2h(val);
}

// ---------------- kernel 2: transpose-cast q/k/v [b][i][n] f32 -> [b][n][i] f16 ------
__global__ __launch_bounds__(256) void k_trans(const float* __restrict__ q,
    const float* __restrict__ k, const float* __restrict__ v, char* __restrict__ ws) {
  int tensor = blockIdx.z >> 2, b = blockIdx.z & 3;
  const float* src = tensor == 0 ? q : (tensor == 1 ? k : v);
  short* dst = (short*)(ws + OFF_XT) + (tensor * 4 + b) * 524288;
  int n0 = blockIdx.x * 64, i0 = blockIdx.y * 64;
  __shared__ float tile[64][65];
  int t = threadIdx.x;
  int nl = t & 63, ib = (t >> 6) * 16;
#pragma unroll
  for (int r = 0; r < 16; ++r)
    tile[ib + r][nl] = src[(b * 256 + i0 + ib + r) * 2048 + n0 + nl];
  __syncthreads();
  int nr = t >> 2, ic = (t & 3) * 16;
  short tmp[16];
#pragma unroll
  for (int j = 0; j < 16; ++j) tmp[j] = f2h(tile[ic + j][nr]);
  short* dp = &dst[(n0 + nr) * 256 + i0 + ic];
  *(s16x8*)dp = *(const s16x8*)&tmp[0];
  *(s16x8*)(dp + 8) = *(const s16x8*)&tmp[8];
}

// ---------------- shared 128x128 GEMM core (K=256), f16 MFMA -------------------------
__device__ __forceinline__ void gemm128(const short* __restrict__ W, const short* __restrict__ X,
                                        int o0, int n0, short* As, short* Bs, f32x4 acc[4][4]) {
  int t = threadIdx.x;
  int lane = t & 63, g = lane >> 4, c = lane & 15, wave = t >> 6;
  int wo = (wave >> 1) * 64, wn = (wave & 1) * 64;
  int row = t >> 2, slot = t & 3;
  for (int kk = 0; kk < 8; ++kk) {
    __syncthreads();
    int koff = kk * 32 + slot * 8;
    *(s16x8*)((char*)As + swz64(row, slot))      = *(const s16x8*)&W[(o0 + row) * 256 + koff];
    *(s16x8*)((char*)As + swz64(row + 64, slot)) = *(const s16x8*)&W[(o0 + row + 64) * 256 + koff];
    *(s16x8*)((char*)Bs + swz64(row, slot))      = *(const s16x8*)&X[(n0 + row) * 256 + koff];
    *(s16x8*)((char*)Bs + swz64(row + 64, slot)) = *(const s16x8*)&X[(n0 + row + 64) * 256 + koff];
    __syncthreads();
    f16x8 af[4], bfr[4];
#pragma unroll
    for (int f = 0; f < 4; ++f) {
      af[f]  = *(const f16x8*)((char*)As + swz64(wo + f * 16 + c, g));
      bfr[f] = *(const f16x8*)((char*)Bs + swz64(wn + f * 16 + c, g));
    }
#pragma unroll
    for (int i = 0; i < 4; ++i)
#pragma unroll
      for (int j = 0; j < 4; ++j)
        acc[i][j] = MFMA(af[i], bfr[j], acc[i][j]);
  }
}

// ---------------- kernel 3: QKV projection + bias + RoPE, write attention layouts ----
__global__ __launch_bounds__(256) void k_proj(const float* __restrict__ enc,
    const float* __restrict__ bq, const float* __restrict__ bk, const float* __restrict__ bv,
    char* __restrict__ ws) {
  int proj = blockIdx.z >> 2, b = blockIdx.z & 3;
  const short* W = (const short*)(ws + OFF_W) + proj * 65536;
  const short* X = (const short*)(ws + OFF_XT) + (proj * 4 + b) * 524288;
  int o0 = blockIdx.y * 128, n0 = blockIdx.x * 128;
  __shared__ short As[128 * 32], Bs[128 * 32];
  f32x4 acc[4][4] = {};
  gemm128(W, X, o0, n0, As, Bs, acc);
  int t = threadIdx.x, lane = t & 63, g = lane >> 4, c = lane & 15, wave = t >> 6;
  int wo = (wave >> 1) * 64, wn = (wave & 1) * 64;
  const float* bias = proj == 0 ? bq : (proj == 1 ? bk : bv);
  if (proj < 2) {
    // RoPE: C-layout rows o = ..+g*4+reg => h = reg, d = (o>>2) lane-constant;
    // pair (d, d±1) lives at lane^16 (g^1), same reg.
    short* dst = (short*)(ws + (proj == 0 ? OFF_QR : OFF_KR));
    float scale = proj == 0 ? 0.125f : 1.0f;  // fold 1/sqrt(64) into Q
    float sgn = (g & 1) ? 1.0f : -1.0f;
#pragma unroll
    for (int i = 0; i < 4; ++i) {
      int ob = o0 + wo + i * 16 + g * 4;
      int d = ob >> 2;
#pragma unroll
      for (int j = 0; j < 4; ++j) {
        int n = n0 + wn + j * 16 + c;
        float cv = enc[n * 64 + d], sv = enc[131072 + n * 64 + d];
#pragma unroll
        for (int r = 0; r < 4; ++r) {
          float val = acc[i][j][r] + bias[ob + r];
          float par = __shfl_xor(val, 16, 64);
          float res = (val * cv + sgn * par * sv) * scale;
          dst[((b * 4 + r) * 2048 + n) * 64 + d] = f2h(res);  // [bh][n][d]
        }
      }
    }
  } else {
    short* dst = (short*)(ws + OFF_VT);
#pragma unroll
    for (int i = 0; i < 4; ++i) {
      int ob = o0 + wo + i * 16 + g * 4;
      int d = ob >> 2;
#pragma unroll
      for (int j = 0; j < 4; ++j) {
        int n = n0 + wn + j * 16 + c;
#pragma unroll
        for (int r = 0; r < 4; ++r) {
          float val = acc[i][j][r] + bias[ob + r];
          dst[((b * 4 + r) * 64 + d) * 2048 + n] = f2h(val);  // [bh][d][m]
        }
      }
    }
  }
}

// ---------------- kernel 4: flash attention per (b,h) --------------------------------
__global__ __launch_bounds__(256) void k_attn(char* __restrict__ ws) {
  int bh = blockIdx.y;
  int t = threadIdx.x, wave = t >> 6, lane = t & 63, g = lane >> 4, c = lane & 15;
  int nw = blockIdx.x * 64 + wave * 16;  // this wave's 16 Q rows
  const short* Q = (const short*)(ws + OFF_QR) + bh * 131072;  // [2048][64]
  const short* K = (const short*)(ws + OFF_KR) + bh * 131072;
  const short* V = (const short*)(ws + OFF_VT) + bh * 131072;  // [64][2048]
  short* XA = (short*)(ws + OFF_XA);
  __shared__ short Ks[64 * 64], Vs[64 * 64], Ps[4][16 * 64];
  char* Pb = (char*)Ps[wave];
  f16x8 qf0 = *(const f16x8*)&Q[(nw + c) * 64 + g * 8];
  f16x8 qf1 = *(const f16x8*)&Q[(nw + c) * 64 + 32 + g * 8];
  f32x4 po[4] = {};
  float mrun[4], lrun[4];
#pragma unroll
  for (int r = 0; r < 4; ++r) { mrun[r] = -1e30f; lrun[r] = 0.f; }
  int sr = t >> 3, sl = t & 7;
  for (int m0 = 0; m0 < 2048; m0 += 64) {
    __syncthreads();
    *(s16x8*)((char*)Ks + swz128(sr, sl))      = *(const s16x8*)&K[(m0 + sr) * 64 + sl * 8];
    *(s16x8*)((char*)Ks + swz128(sr + 32, sl)) = *(const s16x8*)&K[(m0 + sr + 32) * 64 + sl * 8];
    *(s16x8*)((char*)Vs + swz128(sr, sl))      = *(const s16x8*)&V[sr * 2048 + m0 + sl * 8];
    *(s16x8*)((char*)Vs + swz128(sr + 32, sl)) = *(const s16x8*)&V[(sr + 32) * 2048 + m0 + sl * 8];
    __syncthreads();
    // S = Q K^T (Q pre-scaled)
    f32x4 s[4] = {};
#pragma unroll
    for (int fj = 0; fj < 4; ++fj) {
      f16x8 k0 = *(const f16x8*)((char*)Ks + swz128(fj * 16 + c, g));
      f16x8 k1 = *(const f16x8*)((char*)Ks + swz128(fj * 16 + c, 4 + g));
      s[fj] = MFMA(qf0, k0, s[fj]);
      s[fj] = MFMA(qf1, k1, s[fj]);
    }
    // online softmax over the 64-wide tile (rows live on 16-lane groups)
    float pm[4], nm[4], corr[4], rs[4];
#pragma unroll
    for (int r = 0; r < 4; ++r) {
      pm[r] = fmaxf(fmaxf(s[0][r], s[1][r]), fmaxf(s[2][r], s[3][r]));
#pragma unroll
      for (int d_ = 1; d_ < 16; d_ <<= 1) pm[r] = fmaxf(pm[r], __shfl_xor(pm[r], d_, 64));
      nm[r] = fmaxf(mrun[r], pm[r]);
      corr[r] = __expf(mrun[r] - nm[r]);
      mrun[r] = nm[r];
      rs[r] = 0.f;
    }
    float p[4][4];
#pragma unroll
    for (int fj = 0; fj < 4; ++fj)
#pragma unroll
      for (int r = 0; r < 4; ++r) {
        p[fj][r] = __expf(s[fj][r] - nm[r]);
        rs[r] += p[fj][r];
      }
#pragma unroll
    for (int r = 0; r < 4; ++r) {
#pragma unroll
      for (int d_ = 1; d_ < 16; d_ <<= 1) rs[r] += __shfl_xor(rs[r], d_, 64);
      lrun[r] = lrun[r] * corr[r] + rs[r];
    }
#pragma unroll
    for (int fd = 0; fd < 4; ++fd)
#pragma unroll
      for (int r = 0; r < 4; ++r) po[fd][r] *= corr[r];
    // P -> per-wave LDS (f16), then PV
#pragma unroll
    for (int fj = 0; fj < 4; ++fj)
#pragma unroll
      for (int r = 0; r < 4; ++r) {
        int rr = g * 4 + r, mm = fj * 16 + c;
        *(short*)(Pb + swz128(rr, mm >> 3) + (mm & 7) * 2) = f2h(p[fj][r]);
      }
    asm volatile("s_waitcnt lgkmcnt(0)" ::: "memory");
    f16x8 pa0 = *(const f16x8*)(Pb + swz128(c, g));
    f16x8 pa1 = *(const f16x8*)(Pb + swz128(c, 4 + g));
#pragma unroll
    for (int fd = 0; fd < 4; ++fd) {
      int dd = fd * 16 + c;
      f16x8 vb0 = *(const f16x8*)((char*)Vs + swz128(dd, g));
      f16x8 vb1 = *(const f16x8*)((char*)Vs + swz128(dd, 4 + g));
      po[fd] = MFMA(pa0, vb0, po[fd]);
      po[fd] = MFMA(pa1, vb1, po[fd]);
    }
  }
  int b = bh >> 2, h = bh & 3;
#pragma unroll
  for (int fd = 0; fd < 4; ++fd) {
    int d = fd * 16 + c;
#pragma unroll
    for (int r = 0; r < 4; ++r) {
      int n = nw + g * 4 + r;
      float val = po[fd][r] / lrun[r];
      XA[(b * 2048 + n) * 256 + h * 64 + d] = f2h(val);  // [b][n][h*64+d]
    }
  }
}

// ---------------- kernel 5: output projection (fp32 out + bias) ----------------------
__global__ __launch_bounds__(256) void k_final(const float* __restrict__ bm,
    float* __restrict__ out, char* __restrict__ ws) {
  int b = blockIdx.z;
  const short* W = (const short*)(ws + OFF_W) + 3 * 65536;     // Wm reordered
  const short* X = (const short*)(ws + OFF_XA) + b * 524288;   // [2048][256]
  int o0 = blockIdx.y * 128, n0 = blockIdx.x * 128;
  __shared__ short As[128 * 32], Bs[128 * 32];
  f32x4 acc[4][4] = {};
  gemm128(W, X, o0, n0, As, Bs, acc);
  int t = threadIdx.x, lane = t & 63, g = lane >> 4, c = lane & 15, wave = t >> 6;
  int wo = (wave >> 1) * 64, wn = (wave & 1) * 64;
#pragma unroll
  for (int i = 0; i < 4; ++i) {
    int ob = o0 + wo + i * 16 + g * 4;
#pragma unroll
    for (int j = 0; j < 4; ++j) {
      int n = n0 + wn + j * 16 + c;
#pragma unroll
      for (int r = 0; r < 4; ++r)
        out[(b * 256 + ob + r) * 2048 + n] = acc[i][j][r] + bm[ob + r];
    }
  }
}

extern "C" void kernel_launch(void* const* d_in, const int* in_sizes, int n_in,
                              void* d_out, int out_size, void* d_ws, size_t ws_size,
                              hipStream_t stream) {
  (void)in_sizes; (void)n_in; (void)out_size; (void)ws_size;
  const float* q   = (const float*)d_in[0];
  const float* k   = (const float*)d_in[1];
  const float* v   = (const float*)d_in[2];
  const float* enc = (const float*)d_in[3];
  const float* Wq  = (const float*)d_in[4];
  const float* bq  = (const float*)d_in[5];
  const float* Wk  = (const float*)d_in[6];
  const float* bk  = (const float*)d_in[7];
  const float* Wv  = (const float*)d_in[8];
  const float* bv  = (const float*)d_in[9];
  const float* Wm  = (const float*)d_in[10];
  const float* bm  = (const float*)d_in[11];
  char* ws = (char*)d_ws;
  float* out = (float*)d_out;
  hipLaunchKernelGGL(k_convw, dim3(256, 4), dim3(256), 0, stream, Wq, Wk, Wv, Wm, ws);
  hipLaunchKernelGGL(k_trans, dim3(32, 4, 12), dim3(256), 0, stream, q, k, v, ws);
  hipLaunchKernelGGL(k_proj, dim3(16, 2, 12), dim3(256), 0, stream, enc, bq, bk, bv, ws);
  hipLaunchKernelGGL(k_attn, dim3(32, 16), dim3(256), 0, stream, ws);
  hipLaunchKernelGGL(k_final, dim3(16, 2, 4), dim3(256), 0, stream, bm, out, ws);
}

// Round 2
// 182.486 us; speedup vs baseline: 1.0203x; 1.0203x over previous
//
#include <hip/hip_runtime.h>
#include <stdint.h>

#define NSEQ 2048

typedef __attribute__((ext_vector_type(4))) float f32x4;
typedef __attribute__((ext_vector_type(8))) short s16x8;
typedef _Float16 f16x8 __attribute__((ext_vector_type(8)));

// workspace byte offsets
#define OFF_XT  0u            // [3][4][2048][256] f16 = 12 MB (dead after k_proj)
#define OFF_XA  0u            // [4][2048][256] f16 (combine out, k_final in)
#define OFF_PO  4194304u      // [2 split][16 bh][2048][64] f16 = 8 MB (inside old XT)
#define OFF_W   12582912u     // 4 * 65536 f16 = 512 KB
#define OFF_QR  13107200u     // [16][2048][64] f16, 4 MB
#define OFF_KR  17301504u     // [16][2048][64]
#define OFF_VT  21495808u     // [16][64][2048]
#define OFF_M   25690112u     // [2][16][2048] f32 running-max
#define OFF_L   25952256u     // [2][16][2048] f32 running-sum  (ws end: 25 MB)

__device__ __forceinline__ short f2h(float f) {
  _Float16 h = (_Float16)f;
  return __builtin_bit_cast(short, h);
}
__device__ __forceinline__ float h2f(short s) {
  return (float)__builtin_bit_cast(_Float16, s);
}
// 64B-row tiles (GEMM staging, [128][32] f16): spread 4 slots with row bits
__device__ __forceinline__ int swz64(int row, int slot) {
  return row * 64 + ((slot ^ ((row >> 1) & 3)) << 4);
}
// 128B-row tiles (attention, [*][64] f16): classic ^(row&7) on the 16B slot
__device__ __forceinline__ int swz128(int row, int slot) {
  return row * 128 + ((slot ^ (row & 7)) << 4);
}
#define MFMA(a, b, c) __builtin_amdgcn_mfma_f32_16x16x32_f16(a, b, c, 0, 0, 0)

// ---------------- kernel 1: weight cast (+ Wm reorder to k = h*64+d) ----------------
__global__ void k_convw(const float* __restrict__ Wq, const float* __restrict__ Wk,
                        const float* __restrict__ Wv, const float* __restrict__ Wm,
                        char* __restrict__ ws) {
  int o = blockIdx.x, which = blockIdx.y, i = threadIdx.x;
  const float* src = which == 0 ? Wq : which == 1 ? Wk : which == 2 ? Wv : Wm;
  short* dst = (short*)(ws + OFF_W) + which * 65536;
  // Wm_r[o][h*64+d] = Wm[o][d*4+h]
  float val = (which < 3) ? src[o * 256 + i] : src[o * 256 + ((i & 63) << 2) + (i >> 6)];
  dst[o * 256 + i] = f2h(val);
}

// ---------------- kernel 2: transpose-cast q/k/v [b][i][n] f32 -> [b][n][i] f16 ------
__global__ __launch_bounds__(256) void k_trans(const float* __restrict__ q,
    const float* __restrict__ k, const float* __restrict__ v, char* __restrict__ ws) {
  int tensor = blockIdx.z >> 2, b = blockIdx.z & 3;
  const float* src = tensor == 0 ? q : (tensor == 1 ? k : v);
  short* dst = (short*)(ws + OFF_XT) + (tensor * 4 + b) * 524288;
  int n0 = blockIdx.x * 64, i0 = blockIdx.y * 64;
  __shared__ float tile[64][65];
  int t = threadIdx.x;
  int nl = t & 63, ib = (t >> 6) * 16;
#pragma unroll
  for (int r = 0; r < 16; ++r)
    tile[ib + r][nl] = src[(b * 256 + i0 + ib + r) * 2048 + n0 + nl];
  __syncthreads();
  int nr = t >> 2, ic = (t & 3) * 16;
  short tmp[16];
#pragma unroll
  for (int j = 0; j < 16; ++j) tmp[j] = f2h(tile[ic + j][nr]);
  short* dp = &dst[(n0 + nr) * 256 + i0 + ic];
  *(s16x8*)dp = *(const s16x8*)&tmp[0];
  *(s16x8*)(dp + 8) = *(const s16x8*)&tmp[8];
}

// ---------------- shared 128x128 GEMM core (K=256), f16 MFMA -------------------------
__device__ __forceinline__ void gemm128(const short* __restrict__ W, const short* __restrict__ X,
                                        int o0, int n0, short* As, short* Bs, f32x4 acc[4][4]) {
  int t = threadIdx.x;
  int lane = t & 63, g = lane >> 4, c = lane & 15, wave = t >> 6;
  int wo = (wave >> 1) * 64, wn = (wave & 1) * 64;
  int row = t >> 2, slot = t & 3;
  for (int kk = 0; kk < 8; ++kk) {
    __syncthreads();
    int koff = kk * 32 + slot * 8;
    *(s16x8*)((char*)As + swz64(row, slot))      = *(const s16x8*)&W[(o0 + row) * 256 + koff];
    *(s16x8*)((char*)As + swz64(row + 64, slot)) = *(const s16x8*)&W[(o0 + row + 64) * 256 + koff];
    *(s16x8*)((char*)Bs + swz64(row, slot))      = *(const s16x8*)&X[(n0 + row) * 256 + koff];
    *(s16x8*)((char*)Bs + swz64(row + 64, slot)) = *(const s16x8*)&X[(n0 + row + 64) * 256 + koff];
    __syncthreads();
    f16x8 af[4], bfr[4];
#pragma unroll
    for (int f = 0; f < 4; ++f) {
      af[f]  = *(const f16x8*)((char*)As + swz64(wo + f * 16 + c, g));
      bfr[f] = *(const f16x8*)((char*)Bs + swz64(wn + f * 16 + c, g));
    }
#pragma unroll
    for (int i = 0; i < 4; ++i)
#pragma unroll
      for (int j = 0; j < 4; ++j)
        acc[i][j] = MFMA(af[i], bfr[j], acc[i][j]);
  }
}

// ---------------- kernel 3: QKV projection + bias + RoPE, write attention layouts ----
__global__ __launch_bounds__(256) void k_proj(const float* __restrict__ enc,
    const float* __restrict__ bq, const float* __restrict__ bk, const float* __restrict__ bv,
    char* __restrict__ ws) {
  int proj = blockIdx.z >> 2, b = blockIdx.z & 3;
  const short* W = (const short*)(ws + OFF_W) + proj * 65536;
  const short* X = (const short*)(ws + OFF_XT) + (proj * 4 + b) * 524288;
  int o0 = blockIdx.y * 128, n0 = blockIdx.x * 128;
  __shared__ short As[128 * 32], Bs[128 * 32];
  f32x4 acc[4][4] = {};
  gemm128(W, X, o0, n0, As, Bs, acc);
  int t = threadIdx.x, lane = t & 63, g = lane >> 4, c = lane & 15, wave = t >> 6;
  int wo = (wave >> 1) * 64, wn = (wave & 1) * 64;
  const float* bias = proj == 0 ? bq : (proj == 1 ? bk : bv);
  if (proj < 2) {
    // RoPE: C-layout rows o = ..+g*4+reg => h = reg, d = (o>>2) lane-constant;
    // pair (d, d±1) lives at lane^16 (g^1), same reg.
    short* dst = (short*)(ws + (proj == 0 ? OFF_QR : OFF_KR));
    float scale = proj == 0 ? 0.125f : 1.0f;  // fold 1/sqrt(64) into Q
    float sgn = (g & 1) ? 1.0f : -1.0f;
#pragma unroll
    for (int i = 0; i < 4; ++i) {
      int ob = o0 + wo + i * 16 + g * 4;
      int d = ob >> 2;
#pragma unroll
      for (int j = 0; j < 4; ++j) {
        int n = n0 + wn + j * 16 + c;
        float cv = enc[n * 64 + d], sv = enc[131072 + n * 64 + d];
#pragma unroll
        for (int r = 0; r < 4; ++r) {
          float val = acc[i][j][r] + bias[ob + r];
          float par = __shfl_xor(val, 16, 64);
          float res = (val * cv + sgn * par * sv) * scale;
          dst[((b * 4 + r) * 2048 + n) * 64 + d] = f2h(res);  // [bh][n][d]
        }
      }
    }
  } else {
    short* dst = (short*)(ws + OFF_VT);
#pragma unroll
    for (int i = 0; i < 4; ++i) {
      int ob = o0 + wo + i * 16 + g * 4;
      int d = ob >> 2;
#pragma unroll
      for (int j = 0; j < 4; ++j) {
        int n = n0 + wn + j * 16 + c;
#pragma unroll
        for (int r = 0; r < 4; ++r) {
          float val = acc[i][j][r] + bias[ob + r];
          dst[((b * 4 + r) * 64 + d) * 2048 + n] = f2h(val);  // [bh][d][m]
        }
      }
    }
  }
}

// ---------------- kernel 4: flash attention, split-KV x2, reg-prefetched -------------
__global__ __launch_bounds__(256, 4) void k_attn(char* __restrict__ ws) {
  int bh = blockIdx.y, ms = blockIdx.z;
  int t = threadIdx.x, wave = t >> 6, lane = t & 63, g = lane >> 4, c = lane & 15;
  int nw = blockIdx.x * 64 + wave * 16;  // this wave's 16 Q rows
  const short* Q = (const short*)(ws + OFF_QR) + bh * 131072;  // [2048][64]
  const short* K = (const short*)(ws + OFF_KR) + bh * 131072;
  const short* V = (const short*)(ws + OFF_VT) + bh * 131072;  // [64][2048]
  __shared__ short Ks[64 * 64], Vs[64 * 64], Ps[4][16 * 64];
  char* Pb = (char*)Ps[wave];
  f16x8 qf0 = *(const f16x8*)&Q[(nw + c) * 64 + g * 8];
  f16x8 qf1 = *(const f16x8*)&Q[(nw + c) * 64 + 32 + g * 8];
  f32x4 po[4] = {};
  float mrun[4], lrun[4];
#pragma unroll
  for (int r = 0; r < 4; ++r) { mrun[r] = -1e30f; lrun[r] = 0.f; }
  int sr = t >> 3, sl = t & 7;
  const int mb = ms * 1024;

  s16x8 rk0, rk1, rv0, rv1, sk0, sk1, sv0, sv1;
  auto LD = [&](int m0, s16x8& a, s16x8& b2, s16x8& c2, s16x8& d2) {
    a  = *(const s16x8*)&K[(m0 + sr) * 64 + sl * 8];
    b2 = *(const s16x8*)&K[(m0 + sr + 32) * 64 + sl * 8];
    c2 = *(const s16x8*)&V[sr * 2048 + m0 + sl * 8];
    d2 = *(const s16x8*)&V[(sr + 32) * 2048 + m0 + sl * 8];
  };
  auto ST = [&](const s16x8& a, const s16x8& b2, const s16x8& c2, const s16x8& d2) {
    *(s16x8*)((char*)Ks + swz128(sr, sl))      = a;
    *(s16x8*)((char*)Ks + swz128(sr + 32, sl)) = b2;
    *(s16x8*)((char*)Vs + swz128(sr, sl))      = c2;
    *(s16x8*)((char*)Vs + swz128(sr + 32, sl)) = d2;
  };
  auto COMPUTE = [&]() {
    // S = Q K^T (Q pre-scaled)
    f32x4 s[4] = {};
    __builtin_amdgcn_s_setprio(1);
#pragma unroll
    for (int fj = 0; fj < 4; ++fj) {
      f16x8 k0 = *(const f16x8*)((char*)Ks + swz128(fj * 16 + c, g));
      f16x8 k1 = *(const f16x8*)((char*)Ks + swz128(fj * 16 + c, 4 + g));
      s[fj] = MFMA(qf0, k0, s[fj]);
      s[fj] = MFMA(qf1, k1, s[fj]);
    }
    __builtin_amdgcn_s_setprio(0);
    // online softmax over the 64-wide tile (rows live on 16-lane groups)
    float pm[4], nm[4], corr[4], rs[4];
#pragma unroll
    for (int r = 0; r < 4; ++r) {
      pm[r] = fmaxf(fmaxf(s[0][r], s[1][r]), fmaxf(s[2][r], s[3][r]));
#pragma unroll
      for (int d_ = 1; d_ < 16; d_ <<= 1) pm[r] = fmaxf(pm[r], __shfl_xor(pm[r], d_, 64));
      nm[r] = fmaxf(mrun[r], pm[r]);
      corr[r] = __expf(mrun[r] - nm[r]);
      mrun[r] = nm[r];
      rs[r] = 0.f;
    }
    float p[4][4];
#pragma unroll
    for (int fj = 0; fj < 4; ++fj)
#pragma unroll
      for (int r = 0; r < 4; ++r) {
        p[fj][r] = __expf(s[fj][r] - nm[r]);
        rs[r] += p[fj][r];
      }
#pragma unroll
    for (int r = 0; r < 4; ++r) {
#pragma unroll
      for (int d_ = 1; d_ < 16; d_ <<= 1) rs[r] += __shfl_xor(rs[r], d_, 64);
      lrun[r] = lrun[r] * corr[r] + rs[r];
    }
#pragma unroll
    for (int fd = 0; fd < 4; ++fd)
#pragma unroll
      for (int r = 0; r < 4; ++r) po[fd][r] *= corr[r];
    // P -> per-wave LDS (f16), then PV
#pragma unroll
    for (int fj = 0; fj < 4; ++fj)
#pragma unroll
      for (int r = 0; r < 4; ++r) {
        int rr = g * 4 + r, mm = fj * 16 + c;
        *(short*)(Pb + swz128(rr, mm >> 3) + (mm & 7) * 2) = f2h(p[fj][r]);
      }
    asm volatile("s_waitcnt lgkmcnt(0)" ::: "memory");
    __builtin_amdgcn_sched_barrier(0);
    f16x8 pa0 = *(const f16x8*)(Pb + swz128(c, g));
    f16x8 pa1 = *(const f16x8*)(Pb + swz128(c, 4 + g));
    __builtin_amdgcn_s_setprio(1);
#pragma unroll
    for (int fd = 0; fd < 4; ++fd) {
      int dd = fd * 16 + c;
      f16x8 vb0 = *(const f16x8*)((char*)Vs + swz128(dd, g));
      f16x8 vb1 = *(const f16x8*)((char*)Vs + swz128(dd, 4 + g));
      po[fd] = MFMA(pa0, vb0, po[fd]);
      po[fd] = MFMA(pa1, vb1, po[fd]);
    }
    __builtin_amdgcn_s_setprio(0);
  };

  LD(mb, rk0, rk1, rv0, rv1);
  for (int tt = 0; tt < 16; tt += 2) {
    __syncthreads();                 // prior tile's LDS reads complete
    ST(rk0, rk1, rv0, rv1);
    LD(mb + (tt + 1) * 64, sk0, sk1, sv0, sv1);   // prefetch hides under compute
    __syncthreads();
    COMPUTE();
    __syncthreads();
    ST(sk0, sk1, sv0, sv1);
    if (tt + 2 < 16) LD(mb + (tt + 2) * 64, rk0, rk1, rv0, rv1);
    __syncthreads();
    COMPUTE();
  }

  // write normalized partial O + (m, l) for combine
  short* PO = (short*)(ws + OFF_PO);
  float* Mm = (float*)(ws + OFF_M);
  float* Ll = (float*)(ws + OFF_L);
  int base = (ms * 16 + bh) * 2048;
#pragma unroll
  for (int fd = 0; fd < 4; ++fd) {
    int d = fd * 16 + c;
#pragma unroll
    for (int r = 0; r < 4; ++r) {
      int n = nw + g * 4 + r;
      PO[(base + n) * 64 + d] = f2h(po[fd][r] / lrun[r]);
    }
  }
  if (c == 0) {
#pragma unroll
    for (int r = 0; r < 4; ++r) {
      int n = nw + g * 4 + r;
      Mm[base + n] = mrun[r];
      Ll[base + n] = lrun[r];
    }
  }
}

// ---------------- kernel 4b: combine the two KV-split partials -----------------------
__global__ __launch_bounds__(256) void k_comb(char* __restrict__ ws) {
  int t = threadIdx.x;
  int row = blockIdx.x * 32 + (t >> 3);  // bh*2048 + n
  int bh = row >> 11, n = row & 2047;
  int dc = (t & 7) * 8;
  const short* PO = (const short*)(ws + OFF_PO);
  const float* Mm = (const float*)(ws + OFF_M);
  const float* Ll = (const float*)(ws + OFF_L);
  float m1 = Mm[row], m2 = Mm[32768 + row];
  float l1 = Ll[row], l2 = Ll[32768 + row];
  float M = fmaxf(m1, m2);
  float w1 = l1 * __expf(m1 - M), w2 = l2 * __expf(m2 - M);
  float inv = 1.f / (w1 + w2);
  float a1 = w1 * inv, a2 = w2 * inv;
  s16x8 o1 = *(const s16x8*)&PO[row * 64 + dc];
  s16x8 o2 = *(const s16x8*)&PO[(32768 + row) * 64 + dc];
  short res[8];
#pragma unroll
  for (int j = 0; j < 8; ++j) res[j] = f2h(a1 * h2f(o1[j]) + a2 * h2f(o2[j]));
  short* XA = (short*)(ws + OFF_XA);
  int b = bh >> 2, h = bh & 3;
  *(s16x8*)&XA[(b * 2048 + n) * 256 + h * 64 + dc] = *(const s16x8*)res;
}

// ---------------- kernel 5: output projection (fp32 out + bias) ----------------------
__global__ __launch_bounds__(256) void k_final(const float* __restrict__ bm,
    float* __restrict__ out, char* __restrict__ ws) {
  int b = blockIdx.z;
  const short* W = (const short*)(ws + OFF_W) + 3 * 65536;     // Wm reordered
  const short* X = (const short*)(ws + OFF_XA) + b * 524288;   // [2048][256]
  int o0 = blockIdx.y * 128, n0 = blockIdx.x * 128;
  __shared__ short As[128 * 32], Bs[128 * 32];
  f32x4 acc[4][4] = {};
  gemm128(W, X, o0, n0, As, Bs, acc);
  int t = threadIdx.x, lane = t & 63, g = lane >> 4, c = lane & 15, wave = t >> 6;
  int wo = (wave >> 1) * 64, wn = (wave & 1) * 64;
#pragma unroll
  for (int i = 0; i < 4; ++i) {
    int ob = o0 + wo + i * 16 + g * 4;
#pragma unroll
    for (int j = 0; j < 4; ++j) {
      int n = n0 + wn + j * 16 + c;
#pragma unroll
      for (int r = 0; r < 4; ++r)
        out[(b * 256 + ob + r) * 2048 + n] = acc[i][j][r] + bm[ob + r];
    }
  }
}

extern "C" void kernel_launch(void* const* d_in, const int* in_sizes, int n_in,
                              void* d_out, int out_size, void* d_ws, size_t ws_size,
                              hipStream_t stream) {
  (void)in_sizes; (void)n_in; (void)out_size; (void)ws_size;
  const float* q   = (const float*)d_in[0];
  const float* k   = (const float*)d_in[1];
  const float* v   = (const float*)d_in[2];
  const float* enc = (const float*)d_in[3];
  const float* Wq  = (const float*)d_in[4];
  const float* bq  = (const float*)d_in[5];
  const float* Wk  = (const float*)d_in[6];
  const float* bk  = (const float*)d_in[7];
  const float* Wv  = (const float*)d_in[8];
  const float* bv  = (const float*)d_in[9];
  const float* Wm  = (const float*)d_in[10];
  const float* bm  = (const float*)d_in[11];
  char* ws = (char*)d_ws;
  float* out = (float*)d_out;
  hipLaunchKernelGGL(k_convw, dim3(256, 4), dim3(256), 0, stream, Wq, Wk, Wv, Wm, ws);
  hipLaunchKernelGGL(k_trans, dim3(32, 4, 12), dim3(256), 0, stream, q, k, v, ws);
  hipLaunchKernelGGL(k_proj, dim3(16, 2, 12), dim3(256), 0, stream, enc, bq, bk, bv, ws);
  hipLaunchKernelGGL(k_attn, dim3(32, 16, 2), dim3(256), 0, stream, ws);
  hipLaunchKernelGGL(k_comb, dim3(1024), dim3(256), 0, stream, ws);
  hipLaunchKernelGGL(k_final, dim3(16, 2, 4), dim3(256), 0, stream, bm, out, ws);
}